// Round 5
// baseline (521.172 us; speedup 1.0000x reference)
//
#include <hip/hip_runtime.h>
#include <math.h>

#define BN_EPS 1e-5f

constexpr int B  = 4;
constexpr int C  = 256;
constexpr int HW = 4096;   // 64*64
constexpr int CK = 64;
constexpr int CV = 256;
constexpr int CO = 320;    // CK + CV
constexpr int CHG = 2;     // channel groups in attn (128 ch each)
constexpr int JS  = 2;     // j-splits (flash-decoding style)

typedef short bf16x8 __attribute__((ext_vector_type(8)));
typedef float f32x4  __attribute__((ext_vector_type(4)));

__device__ __forceinline__ ushort f2bf(float f) {
    unsigned u = __float_as_uint(f);
    u += 0x7FFFu + ((u >> 16) & 1u);      // round to nearest even
    return (ushort)(u >> 16);
}

// ---------------------------------------------------------------------------
// Kernel 0: fold BN into Wk (row-scale) and emit bf16 weight table
// Wq[co][c], co<64 -> Wk*inv, else Wv; bq[co] = fused bias.
// ---------------------------------------------------------------------------
__global__ __launch_bounds__(256) void wprep(
    const float* __restrict__ Wk, const float* __restrict__ bk,
    const float* __restrict__ gamma, const float* __restrict__ beta,
    const float* __restrict__ mean,  const float* __restrict__ var,
    const float* __restrict__ Wv, const float* __restrict__ bv,
    ushort* __restrict__ Wq, float* __restrict__ bq)
{
    const int co = blockIdx.x;
    const int c  = threadIdx.x;
    float w;
    if (co < CK) {
        float inv = gamma[co] * rsqrtf(var[co] + BN_EPS);
        w = Wk[co * C + c] * inv;
        if (c == 0) bq[co] = bk[co] * inv + (beta[co] - mean[co] * inv);
    } else {
        w = Wv[(co - CK) * C + c];
        if (c == 0) bq[co] = bv[co - CK];
    }
    Wq[co * C + c] = f2bf(w);
}

// ---------------------------------------------------------------------------
// Kernel 1: KV projection as MFMA GEMM.  D[co][hw] = W' . x  (+ bias)
// Block: 32-hw tile, all 320 co, 4 waves x 5 m-tiles. x staged fp32->bf16
// transposed into LDS once (1 barrier). A-frags direct from bf16 Wq (L2).
// K -> Kbuf[b][hw][ck] (b64 transposed store), V -> Vbuf[b][cv][hw].
// Fused: per-row K norms (wave 0) + per-batch max norm (Cauchy-Schwarz bound).
// ---------------------------------------------------------------------------
__global__ __launch_bounds__(256) void kv_gemm(
    const float* __restrict__ x, const ushort* __restrict__ Wq,
    const float* __restrict__ bq,
    ushort* __restrict__ Kbuf, ushort* __restrict__ Vbuf,
    float* __restrict__ mb, unsigned* __restrict__ Mx)
{
    __shared__ __align__(16) ushort xt[32][C + 8];   // [hw][c] bf16, pad 8

    const int t    = threadIdx.x;
    const int lane = t & 63;
    const int wv   = t >> 6;
    const int q    = lane >> 4;
    const int col  = lane & 15;
    const int hw0  = blockIdx.x * 32;
    const int b    = blockIdx.y;

    const float* xb = x + (size_t)b * C * HW;

    // stage x tile: 4 strided dword loads -> pack bf16x4 -> b64 LDS write
    {
        const int cq  = (t >> 5) * 4;    // 0,4,...,28
        const int hwo = t & 31;
#pragma unroll
        for (int pass = 0; pass < 8; pass++) {
            const int c0 = pass * 32;
            float a0 = xb[(size_t)(c0 + cq + 0) * HW + hw0 + hwo];
            float a1 = xb[(size_t)(c0 + cq + 1) * HW + hw0 + hwo];
            float a2 = xb[(size_t)(c0 + cq + 2) * HW + hw0 + hwo];
            float a3 = xb[(size_t)(c0 + cq + 3) * HW + hw0 + hwo];
            ushort4 u = make_ushort4(f2bf(a0), f2bf(a1), f2bf(a2), f2bf(a3));
            *(ushort4*)&xt[hwo][c0 + cq] = u;
        }
    }
    __syncthreads();

    // K-loop: 8 steps of k=32; per wave 5 m-tiles x 2 n-tiles
    f32x4 acc[5][2];
#pragma unroll
    for (int mi = 0; mi < 5; mi++)
#pragma unroll
        for (int nt = 0; nt < 2; nt++)
            acc[mi][nt] = (f32x4){0.f, 0.f, 0.f, 0.f};

#pragma unroll
    for (int ks = 0; ks < 8; ks++) {
        bf16x8 av[5], bvv[2];
#pragma unroll
        for (int mi = 0; mi < 5; mi++)
            av[mi] = *(const bf16x8*)(Wq + (size_t)(wv * 80 + mi * 16 + col) * C + ks * 32 + q * 8);
#pragma unroll
        for (int nt = 0; nt < 2; nt++)
            bvv[nt] = *(const bf16x8*)&xt[nt * 16 + col][ks * 32 + q * 8];
#pragma unroll
        for (int mi = 0; mi < 5; mi++)
#pragma unroll
            for (int nt = 0; nt < 2; nt++)
                acc[mi][nt] = __builtin_amdgcn_mfma_f32_16x16x32_bf16(av[mi], bvv[nt], acc[mi][nt], 0, 0, 0);
    }

    // epilogue + fused norms
    float ssq[2] = {0.f, 0.f};
#pragma unroll
    for (int mi = 0; mi < 5; mi++) {
        const int cot = wv * 80 + mi * 16;
        float bi[4];
#pragma unroll
        for (int r = 0; r < 4; r++) bi[r] = bq[cot + q * 4 + r];
#pragma unroll
        for (int nt = 0; nt < 2; nt++) {
            const int hw = hw0 + nt * 16 + col;
            float v0 = acc[mi][nt][0] + bi[0];
            float v1 = acc[mi][nt][1] + bi[1];
            float v2 = acc[mi][nt][2] + bi[2];
            float v3 = acc[mi][nt][3] + bi[3];
            if (cot < CK) {           // K tiles (wave 0, mi 0..3): transposed b64 store
                ushort4 kk = make_ushort4(f2bf(v0), f2bf(v1), f2bf(v2), f2bf(v3));
                *(ushort4*)&Kbuf[((size_t)b * HW + hw) * CK + cot + q * 4] = kk;
                ssq[nt] += v0 * v0 + v1 * v1 + v2 * v2 + v3 * v3;
            } else {
                const int cv = cot - CK + q * 4;
                Vbuf[((size_t)b * CV + cv + 0) * HW + hw] = f2bf(v0);
                Vbuf[((size_t)b * CV + cv + 1) * HW + hw] = f2bf(v1);
                Vbuf[((size_t)b * CV + cv + 2) * HW + hw] = f2bf(v2);
                Vbuf[((size_t)b * CV + cv + 3) * HW + hw] = f2bf(v3);
            }
        }
    }

    if (wv == 0) {
        float mxn = 0.f;
#pragma unroll
        for (int nt = 0; nt < 2; nt++) {
            float ss = ssq[nt];
            ss += __shfl_xor(ss, 16, 64);
            ss += __shfl_xor(ss, 32, 64);
            float nr = sqrtf(ss);
            if (lane < 16) mb[(size_t)b * HW + hw0 + nt * 16 + col] = nr;
            mxn = fmaxf(mxn, nr);
        }
#pragma unroll
        for (int off = 1; off <= 32; off <<= 1)
            mxn = fmaxf(mxn, __shfl_xor(mxn, off, 64));
        if (t == 0) atomicMax(Mx + b, __float_as_uint(mxn));
    }
}

// ---------------------------------------------------------------------------
// Kernel 2: MFMA flash attention, bound-softmax, static double-buffered K,
// j-split across JS blocks (partials add — same bound per row), fp32
// atomicAdd into zeroed out; l into Lbuf; norm_out divides at the end.
// ---------------------------------------------------------------------------
#define ATTN_TILE(KC, KN, J0, JN)                                              \
    {                                                                          \
        const int j0_ = (J0), jn_ = (JN);                                      \
        _Pragma("unroll")                                                      \
        for (int nt = 0; nt < 4; nt++)                                         \
            _Pragma("unroll")                                                  \
            for (int k = 0; k < 2; k++)                                        \
                KN[nt][k] = *(const bf16x8*)(Kb + (size_t)(jn_ + nt * 16 + col) * CK + k * 32 + q * 8); \
        bf16x8 vf[2][2];                                                       \
        _Pragma("unroll")                                                      \
        for (int mt = 0; mt < 2; mt++)                                         \
            _Pragma("unroll")                                                  \
            for (int k = 0; k < 2; k++)                                        \
                vf[mt][k] = *(const bf16x8*)(Vb + (size_t)(cbase + mt * 16 + col) * HW + j0_ + k * 32 + q * 8); \
        f32x4 S[4];                                                            \
        _Pragma("unroll")                                                      \
        for (int nt = 0; nt < 4; nt++) {                                       \
            S[nt] = __builtin_amdgcn_mfma_f32_16x16x32_bf16(qa[0], KC[nt][0], zf, 0, 0, 0); \
            S[nt] = __builtin_amdgcn_mfma_f32_16x16x32_bf16(qa[1], KC[nt][1], S[nt], 0, 0, 0); \
        }                                                                      \
        float p[4][4];                                                         \
        _Pragma("unroll")                                                      \
        for (int nt = 0; nt < 4; nt++)                                         \
            _Pragma("unroll")                                                  \
            for (int r = 0; r < 4; r++)                                        \
                p[nt][r] = __expf(S[nt][r] - m_i[r]);                          \
        _Pragma("unroll")                                                      \
        for (int r = 0; r < 4; r++)                                            \
            l_r[r] += (p[0][r] + p[1][r]) + (p[2][r] + p[3][r]);               \
        __syncthreads();                                                       \
        _Pragma("unroll")                                                      \
        for (int nt = 0; nt < 4; nt++)                                         \
            _Pragma("unroll")                                                  \
            for (int r = 0; r < 4; r++)                                        \
                Ps[wv * 16 + q * 4 + r][nt * 16 + col] = f2bf(p[nt][r]);       \
        __syncthreads();                                                       \
        bf16x8 pf[4][2];                                                       \
        _Pragma("unroll")                                                      \
        for (int nt = 0; nt < 4; nt++)                                         \
            _Pragma("unroll")                                                  \
            for (int k = 0; k < 2; k++)                                        \
                pf[nt][k] = *(const bf16x8*)&Ps[nt * 16 + col][k * 32 + q * 8]; \
        _Pragma("unroll")                                                      \
        for (int mt = 0; mt < 2; mt++)                                         \
            _Pragma("unroll")                                                  \
            for (int nt = 0; nt < 4; nt++) {                                   \
                Oacc[mt][nt] = __builtin_amdgcn_mfma_f32_16x16x32_bf16(vf[mt][0], pf[nt][0], Oacc[mt][nt], 0, 0, 0); \
                Oacc[mt][nt] = __builtin_amdgcn_mfma_f32_16x16x32_bf16(vf[mt][1], pf[nt][1], Oacc[mt][nt], 0, 0, 0); \
            }                                                                  \
    }

__global__ __launch_bounds__(256, 4) void attn_kernel(
    const ushort* __restrict__ Kbuf, const ushort* __restrict__ Vbuf,
    const float* __restrict__ mb, const unsigned* __restrict__ Mx,
    float* __restrict__ out, float* __restrict__ Lbuf)
{
    __shared__ __align__(16) ushort Ps[64][72];   // [i][j] bf16, pad 72

    const int t    = threadIdx.x;
    const int lane = t & 63;
    const int wv   = t >> 6;          // 0..3
    const int q    = lane >> 4;       // quad 0..3
    const int col  = lane & 15;
    const int b    = blockIdx.z;
    const int chg  = blockIdx.y & (CHG - 1);
    const int js   = blockIdx.y / CHG;
    const int i0g  = blockIdx.x * 64;
    const int jbase = js * (HW / JS);

    const ushort* Kb = Kbuf + (size_t)b * HW * CK;
    const ushort* Vb = Vbuf + (size_t)b * CV * HW;

    // Q A-frags: A[m=i][k=ck]
    bf16x8 qa[2];
#pragma unroll
    for (int k = 0; k < 2; k++)
        qa[k] = *(const bf16x8*)(Kb + (size_t)(i0g + wv * 16 + col) * CK + k * 32 + q * 8);

    // per-row exp bound
    const float Mxf = __uint_as_float(Mx[b]);
    float m_i[4];
#pragma unroll
    for (int r = 0; r < 4; r++)
        m_i[r] = mb[(size_t)b * HW + i0g + wv * 16 + q * 4 + r] * Mxf;

    f32x4 Oacc[2][4];
#pragma unroll
    for (int mt = 0; mt < 2; mt++)
#pragma unroll
        for (int nt = 0; nt < 4; nt++)
            Oacc[mt][nt] = (f32x4){0.f, 0.f, 0.f, 0.f};

    float l_r[4] = {0.f, 0.f, 0.f, 0.f};
    const f32x4 zf = (f32x4){0.f, 0.f, 0.f, 0.f};
    const int cbase = chg * 128 + wv * 32;

    // preload K tile 0 (static dbuf)
    bf16x8 kf0[4][2], kf1[4][2];
#pragma unroll
    for (int nt = 0; nt < 4; nt++)
#pragma unroll
        for (int k = 0; k < 2; k++)
            kf0[nt][k] = *(const bf16x8*)(Kb + (size_t)(jbase + nt * 16 + col) * CK + k * 32 + q * 8);

    for (int j0 = jbase; j0 < jbase + HW / JS; j0 += 128) {
        ATTN_TILE(kf0, kf1, j0,      j0 + 64);
        ATTN_TILE(kf1, kf0, j0 + 64, (j0 + 128) & (HW - 1));
    }

    // l partials: reduce over 16 col-lanes, one atomicAdd per row (chg 0 only)
#pragma unroll
    for (int r = 0; r < 4; r++) {
        float v = l_r[r];
#pragma unroll
        for (int off = 1; off <= 8; off <<= 1)
            v += __shfl_xor(v, off, 64);
        if (chg == 0 && col == 0)
            atomicAdd(Lbuf + (size_t)b * HW + i0g + wv * 16 + q * 4 + r, v);
    }

    // O partials: fp32 atomicAdd into out (js splits collide; chg disjoint)
    float* ob = out + (size_t)b * CV * HW;
#pragma unroll
    for (int mt = 0; mt < 2; mt++)
#pragma unroll
        for (int r = 0; r < 4; r++) {
            size_t c = cbase + mt * 16 + q * 4 + r;
#pragma unroll
            for (int nt = 0; nt < 4; nt++)
                atomicAdd(&ob[c * HW + i0g + nt * 16 + col], Oacc[mt][nt][r]);
        }
}

// ---------------------------------------------------------------------------
// Kernel 3: out[b][c][i] /= L[b][i]
// ---------------------------------------------------------------------------
__global__ __launch_bounds__(256) void norm_out(
    float* __restrict__ out, const float* __restrict__ Lbuf)
{
    const int g    = blockIdx.x * 256 + threadIdx.x;   // float4 index
    const int flat = g * 4;
    const int i    = flat & (HW - 1);
    const int b    = flat >> 20;                       // / (CV*HW)
    float4 o = *(float4*)&out[flat];
    const float4 l4 = *(const float4*)&Lbuf[(size_t)b * HW + i];
    o.x /= l4.x; o.y /= l4.y; o.z /= l4.z; o.w /= l4.w;
    *(float4*)&out[flat] = o;
}

// ---------------------------------------------------------------------------
extern "C" void kernel_launch(void* const* d_in, const int* in_sizes, int n_in,
                              void* d_out, int out_size, void* d_ws, size_t ws_size,
                              hipStream_t stream)
{
    const float* x     = (const float*)d_in[0];
    const float* Wk    = (const float*)d_in[1];
    const float* bk    = (const float*)d_in[2];
    const float* gamma = (const float*)d_in[3];
    const float* beta  = (const float*)d_in[4];
    const float* mean  = (const float*)d_in[5];
    const float* var   = (const float*)d_in[6];
    const float* Wv    = (const float*)d_in[7];
    const float* bv    = (const float*)d_in[8];
    float* out = (float*)d_out;

    ushort*   Kbuf = (ushort*)d_ws;                          // [B][HW][CK]  2 MB
    ushort*   Vbuf = Kbuf + (size_t)B * HW * CK;             // [B][CV][HW]  8.4 MB
    ushort*   Wq   = Vbuf + (size_t)B * CV * HW;             // [320][256]   160 KB
    float*    bq   = (float*)(Wq + (size_t)CO * C);          // [320]
    float*    mb   = bq + CO;                                // [B][HW]
    float*    Lbuf = mb + (size_t)B * HW;                    // [B][HW]
    unsigned* Mx   = (unsigned*)(Lbuf + (size_t)B * HW);     // [B]

    hipMemsetAsync(Mx, 0, B * sizeof(unsigned), stream);
    hipMemsetAsync(Lbuf, 0, (size_t)B * HW * sizeof(float), stream);
    hipMemsetAsync(out, 0, (size_t)out_size * sizeof(float), stream);

    wprep<<<dim3(CO), 256, 0, stream>>>(Wk, bk, gamma, beta, mean, var, Wv, bv, Wq, bq);

    kv_gemm<<<dim3(HW / 32, B), 256, 0, stream>>>(x, Wq, bq, Kbuf, Vbuf, mb, Mx);

    dim3 g2(HW / 64, CHG * JS, B);                           // (64,4,4) = 1024 blocks
    attn_kernel<<<g2, 256, 0, stream>>>(Kbuf, Vbuf, mb, Mx, out, Lbuf);

    norm_out<<<dim3(out_size / 4 / 256), 256, 0, stream>>>(out, Lbuf);
}

// Round 6
// 294.582 us; speedup vs baseline: 1.7692x; 1.7692x over previous
//
#include <hip/hip_runtime.h>
#include <math.h>

#define BN_EPS 1e-5f

constexpr int B  = 4;
constexpr int C  = 256;
constexpr int HW = 4096;   // 64*64
constexpr int CK = 64;
constexpr int CV = 256;
constexpr int CO = 320;    // CK + CV
constexpr int CHG = 2;     // channel groups in attn (128 ch each)
constexpr int JS  = 2;     // j-splits (flash-decoding style)

typedef short bf16x8 __attribute__((ext_vector_type(8)));
typedef float f32x4  __attribute__((ext_vector_type(4)));

__device__ __forceinline__ ushort f2bf(float f) {
    unsigned u = __float_as_uint(f);
    u += 0x7FFFu + ((u >> 16) & 1u);      // round to nearest even
    return (ushort)(u >> 16);
}

// ---------------------------------------------------------------------------
// Kernel 0: fold BN into Wk (row-scale) and emit bf16 weight table
// ---------------------------------------------------------------------------
__global__ __launch_bounds__(256) void wprep(
    const float* __restrict__ Wk, const float* __restrict__ bk,
    const float* __restrict__ gamma, const float* __restrict__ beta,
    const float* __restrict__ mean,  const float* __restrict__ var,
    const float* __restrict__ Wv, const float* __restrict__ bv,
    ushort* __restrict__ Wq, float* __restrict__ bq)
{
    const int co = blockIdx.x;
    const int c  = threadIdx.x;
    float w;
    if (co < CK) {
        float inv = gamma[co] * rsqrtf(var[co] + BN_EPS);
        w = Wk[co * C + c] * inv;
        if (c == 0) bq[co] = bk[co] * inv + (beta[co] - mean[co] * inv);
    } else {
        w = Wv[(co - CK) * C + c];
        if (c == 0) bq[co] = bv[co - CK];
    }
    Wq[co * C + c] = f2bf(w);
}

// ---------------------------------------------------------------------------
// Kernel 1: KV projection as MFMA GEMM + fused K-norms (Cauchy-Schwarz bound).
// ---------------------------------------------------------------------------
__global__ __launch_bounds__(256) void kv_gemm(
    const float* __restrict__ x, const ushort* __restrict__ Wq,
    const float* __restrict__ bq,
    ushort* __restrict__ Kbuf, ushort* __restrict__ Vbuf,
    float* __restrict__ mb, unsigned* __restrict__ Mx)
{
    __shared__ __align__(16) ushort xt[32][C + 8];   // [hw][c] bf16, pad 8

    const int t    = threadIdx.x;
    const int lane = t & 63;
    const int wv   = t >> 6;
    const int q    = lane >> 4;
    const int col  = lane & 15;
    const int hw0  = blockIdx.x * 32;
    const int b    = blockIdx.y;

    const float* xb = x + (size_t)b * C * HW;

    // stage x tile: strided dword loads -> pack bf16x4 -> b64 LDS write
    {
        const int cq  = (t >> 5) * 4;    // 0,4,...,28
        const int hwo = t & 31;
#pragma unroll
        for (int pass = 0; pass < 8; pass++) {
            const int c0 = pass * 32;
            float a0 = xb[(size_t)(c0 + cq + 0) * HW + hw0 + hwo];
            float a1 = xb[(size_t)(c0 + cq + 1) * HW + hw0 + hwo];
            float a2 = xb[(size_t)(c0 + cq + 2) * HW + hw0 + hwo];
            float a3 = xb[(size_t)(c0 + cq + 3) * HW + hw0 + hwo];
            ushort4 u = make_ushort4(f2bf(a0), f2bf(a1), f2bf(a2), f2bf(a3));
            *(ushort4*)&xt[hwo][c0 + cq] = u;
        }
    }
    __syncthreads();

    f32x4 acc[5][2];
#pragma unroll
    for (int mi = 0; mi < 5; mi++)
#pragma unroll
        for (int nt = 0; nt < 2; nt++)
            acc[mi][nt] = (f32x4){0.f, 0.f, 0.f, 0.f};

#pragma unroll
    for (int ks = 0; ks < 8; ks++) {
        bf16x8 av[5], bvv[2];
#pragma unroll
        for (int mi = 0; mi < 5; mi++)
            av[mi] = *(const bf16x8*)(Wq + (size_t)(wv * 80 + mi * 16 + col) * C + ks * 32 + q * 8);
#pragma unroll
        for (int nt = 0; nt < 2; nt++)
            bvv[nt] = *(const bf16x8*)&xt[nt * 16 + col][ks * 32 + q * 8];
#pragma unroll
        for (int mi = 0; mi < 5; mi++)
#pragma unroll
            for (int nt = 0; nt < 2; nt++)
                acc[mi][nt] = __builtin_amdgcn_mfma_f32_16x16x32_bf16(av[mi], bvv[nt], acc[mi][nt], 0, 0, 0);
    }

    float ssq[2] = {0.f, 0.f};
#pragma unroll
    for (int mi = 0; mi < 5; mi++) {
        const int cot = wv * 80 + mi * 16;
        float bi[4];
#pragma unroll
        for (int r = 0; r < 4; r++) bi[r] = bq[cot + q * 4 + r];
#pragma unroll
        for (int nt = 0; nt < 2; nt++) {
            const int hw = hw0 + nt * 16 + col;
            float v0 = acc[mi][nt][0] + bi[0];
            float v1 = acc[mi][nt][1] + bi[1];
            float v2 = acc[mi][nt][2] + bi[2];
            float v3 = acc[mi][nt][3] + bi[3];
            if (cot < CK) {           // K tiles: transposed b64 store
                ushort4 kk = make_ushort4(f2bf(v0), f2bf(v1), f2bf(v2), f2bf(v3));
                *(ushort4*)&Kbuf[((size_t)b * HW + hw) * CK + cot + q * 4] = kk;
                ssq[nt] += v0 * v0 + v1 * v1 + v2 * v2 + v3 * v3;
            } else {
                const int cv = cot - CK + q * 4;
                Vbuf[((size_t)b * CV + cv + 0) * HW + hw] = f2bf(v0);
                Vbuf[((size_t)b * CV + cv + 1) * HW + hw] = f2bf(v1);
                Vbuf[((size_t)b * CV + cv + 2) * HW + hw] = f2bf(v2);
                Vbuf[((size_t)b * CV + cv + 3) * HW + hw] = f2bf(v3);
            }
        }
    }

    if (wv == 0) {
        float mxn = 0.f;
#pragma unroll
        for (int nt = 0; nt < 2; nt++) {
            float ss = ssq[nt];
            ss += __shfl_xor(ss, 16, 64);
            ss += __shfl_xor(ss, 32, 64);
            float nr = sqrtf(ss);
            if (lane < 16) mb[(size_t)b * HW + hw0 + nt * 16 + col] = nr;
            mxn = fmaxf(mxn, nr);
        }
#pragma unroll
        for (int off = 1; off <= 32; off <<= 1)
            mxn = fmaxf(mxn, __shfl_xor(mxn, off, 64));
        if (t == 0) atomicMax(Mx + b, __float_as_uint(mxn));
    }
}

// ---------------------------------------------------------------------------
// Kernel 2: MFMA flash attention, bound-softmax, static double-buffered K,
// j-split (partials add), fp32 atomicAdd epilogue. launch_bounds(256,2):
// R5's (256,4) capped regs at 128 -> fragment spill (1.2 GB scratch writes);
// ~90 VGPR actual still lets HW co-schedule 4 blocks/CU from the 1024 grid.
// ---------------------------------------------------------------------------
#define ATTN_TILE(KC, KN, J0, JN)                                              \
    {                                                                          \
        const int j0_ = (J0), jn_ = (JN);                                      \
        _Pragma("unroll")                                                      \
        for (int nt = 0; nt < 4; nt++)                                         \
            _Pragma("unroll")                                                  \
            for (int k = 0; k < 2; k++)                                        \
                KN[nt][k] = *(const bf16x8*)(Kb + (size_t)(jn_ + nt * 16 + col) * CK + k * 32 + q * 8); \
        bf16x8 vf[2][2];                                                       \
        _Pragma("unroll")                                                      \
        for (int mt = 0; mt < 2; mt++)                                         \
            _Pragma("unroll")                                                  \
            for (int k = 0; k < 2; k++)                                        \
                vf[mt][k] = *(const bf16x8*)(Vb + (size_t)(cbase + mt * 16 + col) * HW + j0_ + k * 32 + q * 8); \
        f32x4 S[4];                                                            \
        _Pragma("unroll")                                                      \
        for (int nt = 0; nt < 4; nt++) {                                       \
            S[nt] = __builtin_amdgcn_mfma_f32_16x16x32_bf16(qa[0], KC[nt][0], zf, 0, 0, 0); \
            S[nt] = __builtin_amdgcn_mfma_f32_16x16x32_bf16(qa[1], KC[nt][1], S[nt], 0, 0, 0); \
        }                                                                      \
        float p[4][4];                                                         \
        _Pragma("unroll")                                                      \
        for (int nt = 0; nt < 4; nt++)                                         \
            _Pragma("unroll")                                                  \
            for (int r = 0; r < 4; r++)                                        \
                p[nt][r] = __expf(S[nt][r] - m_i[r]);                          \
        _Pragma("unroll")                                                      \
        for (int r = 0; r < 4; r++)                                            \
            l_r[r] += (p[0][r] + p[1][r]) + (p[2][r] + p[3][r]);               \
        __syncthreads();                                                       \
        _Pragma("unroll")                                                      \
        for (int nt = 0; nt < 4; nt++)                                         \
            _Pragma("unroll")                                                  \
            for (int r = 0; r < 4; r++)                                        \
                Ps[wv * 16 + q * 4 + r][nt * 16 + col] = f2bf(p[nt][r]);       \
        __syncthreads();                                                       \
        bf16x8 pf[4][2];                                                       \
        _Pragma("unroll")                                                      \
        for (int nt = 0; nt < 4; nt++)                                         \
            _Pragma("unroll")                                                  \
            for (int k = 0; k < 2; k++)                                        \
                pf[nt][k] = *(const bf16x8*)&Ps[nt * 16 + col][k * 32 + q * 8]; \
        _Pragma("unroll")                                                      \
        for (int mt = 0; mt < 2; mt++)                                         \
            _Pragma("unroll")                                                  \
            for (int nt = 0; nt < 4; nt++) {                                   \
                Oacc[mt][nt] = __builtin_amdgcn_mfma_f32_16x16x32_bf16(vf[mt][0], pf[nt][0], Oacc[mt][nt], 0, 0, 0); \
                Oacc[mt][nt] = __builtin_amdgcn_mfma_f32_16x16x32_bf16(vf[mt][1], pf[nt][1], Oacc[mt][nt], 0, 0, 0); \
            }                                                                  \
    }

__global__ __launch_bounds__(256, 2) void attn_kernel(
    const ushort* __restrict__ Kbuf, const ushort* __restrict__ Vbuf,
    const float* __restrict__ mb, const unsigned* __restrict__ Mx,
    float* __restrict__ out, float* __restrict__ Lbuf)
{
    __shared__ __align__(16) ushort Ps[64][72];   // [i][j] bf16, pad 72

    const int t    = threadIdx.x;
    const int lane = t & 63;
    const int wv   = t >> 6;          // 0..3
    const int q    = lane >> 4;       // quad 0..3
    const int col  = lane & 15;
    const int b    = blockIdx.z;
    const int chg  = blockIdx.y & (CHG - 1);
    const int js   = blockIdx.y / CHG;
    const int i0g  = blockIdx.x * 64;
    const int jbase = js * (HW / JS);

    const ushort* Kb = Kbuf + (size_t)b * HW * CK;
    const ushort* Vb = Vbuf + (size_t)b * CV * HW;

    // Q A-frags: A[m=i][k=ck]
    bf16x8 qa[2];
#pragma unroll
    for (int k = 0; k < 2; k++)
        qa[k] = *(const bf16x8*)(Kb + (size_t)(i0g + wv * 16 + col) * CK + k * 32 + q * 8);

    // per-row exp bound
    const float Mxf = __uint_as_float(Mx[b]);
    float m_i[4];
#pragma unroll
    for (int r = 0; r < 4; r++)
        m_i[r] = mb[(size_t)b * HW + i0g + wv * 16 + q * 4 + r] * Mxf;

    f32x4 Oacc[2][4];
#pragma unroll
    for (int mt = 0; mt < 2; mt++)
#pragma unroll
        for (int nt = 0; nt < 4; nt++)
            Oacc[mt][nt] = (f32x4){0.f, 0.f, 0.f, 0.f};

    float l_r[4] = {0.f, 0.f, 0.f, 0.f};
    const f32x4 zf = (f32x4){0.f, 0.f, 0.f, 0.f};
    const int cbase = chg * 128 + wv * 32;

    // preload K tile 0 (static dbuf)
    bf16x8 kf0[4][2], kf1[4][2];
#pragma unroll
    for (int nt = 0; nt < 4; nt++)
#pragma unroll
        for (int k = 0; k < 2; k++)
            kf0[nt][k] = *(const bf16x8*)(Kb + (size_t)(jbase + nt * 16 + col) * CK + k * 32 + q * 8);

    for (int j0 = jbase; j0 < jbase + HW / JS; j0 += 128) {
        ATTN_TILE(kf0, kf1, j0,      j0 + 64);
        ATTN_TILE(kf1, kf0, j0 + 64, (j0 + 128) & (HW - 1));
    }

    // l partials: reduce over 16 col-lanes, one atomicAdd per row (chg 0 only)
#pragma unroll
    for (int r = 0; r < 4; r++) {
        float v = l_r[r];
#pragma unroll
        for (int off = 1; off <= 8; off <<= 1)
            v += __shfl_xor(v, off, 64);
        if (chg == 0 && col == 0)
            atomicAdd(Lbuf + (size_t)b * HW + i0g + wv * 16 + q * 4 + r, v);
    }

    // O partials: fp32 atomicAdd into out (js splits collide; chg disjoint)
    float* ob = out + (size_t)b * CV * HW;
#pragma unroll
    for (int mt = 0; mt < 2; mt++)
#pragma unroll
        for (int r = 0; r < 4; r++) {
            size_t c = cbase + mt * 16 + q * 4 + r;
#pragma unroll
            for (int nt = 0; nt < 4; nt++)
                atomicAdd(&ob[c * HW + i0g + nt * 16 + col], Oacc[mt][nt][r]);
        }
}

// ---------------------------------------------------------------------------
// Kernel 3: out[b][c][i] /= L[b][i]
// ---------------------------------------------------------------------------
__global__ __launch_bounds__(256) void norm_out(
    float* __restrict__ out, const float* __restrict__ Lbuf)
{
    const int g    = blockIdx.x * 256 + threadIdx.x;   // float4 index
    const int flat = g * 4;
    const int i    = flat & (HW - 1);
    const int b    = flat >> 20;                       // / (CV*HW)
    float4 o = *(float4*)&out[flat];
    const float4 l4 = *(const float4*)&Lbuf[(size_t)b * HW + i];
    o.x /= l4.x; o.y /= l4.y; o.z /= l4.z; o.w /= l4.w;
    *(float4*)&out[flat] = o;
}

// ---------------------------------------------------------------------------
extern "C" void kernel_launch(void* const* d_in, const int* in_sizes, int n_in,
                              void* d_out, int out_size, void* d_ws, size_t ws_size,
                              hipStream_t stream)
{
    const float* x     = (const float*)d_in[0];
    const float* Wk    = (const float*)d_in[1];
    const float* bk    = (const float*)d_in[2];
    const float* gamma = (const float*)d_in[3];
    const float* beta  = (const float*)d_in[4];
    const float* mean  = (const float*)d_in[5];
    const float* var   = (const float*)d_in[6];
    const float* Wv    = (const float*)d_in[7];
    const float* bv    = (const float*)d_in[8];
    float* out = (float*)d_out;

    ushort*   Kbuf = (ushort*)d_ws;                          // [B][HW][CK]  2 MB
    ushort*   Vbuf = Kbuf + (size_t)B * HW * CK;             // [B][CV][HW]  8.4 MB
    ushort*   Wq   = Vbuf + (size_t)B * CV * HW;             // [320][256]   160 KB
    float*    bq   = (float*)(Wq + (size_t)CO * C);          // [320]
    float*    mb   = bq + CO;                                // [B][HW]
    float*    Lbuf = mb + (size_t)B * HW;                    // [B][HW]
    unsigned* Mx   = (unsigned*)(Lbuf + (size_t)B * HW);     // [B]

    hipMemsetAsync(Mx, 0, B * sizeof(unsigned), stream);
    hipMemsetAsync(Lbuf, 0, (size_t)B * HW * sizeof(float), stream);
    hipMemsetAsync(out, 0, (size_t)out_size * sizeof(float), stream);

    wprep<<<dim3(CO), 256, 0, stream>>>(Wk, bk, gamma, beta, mean, var, Wv, bv, Wq, bq);

    kv_gemm<<<dim3(HW / 32, B), 256, 0, stream>>>(x, Wq, bq, Kbuf, Vbuf, mb, Mx);

    dim3 g2(HW / 64, CHG * JS, B);                           // (64,4,4) = 1024 blocks
    attn_kernel<<<g2, 256, 0, stream>>>(Kbuf, Vbuf, mb, Mx, out, Lbuf);

    norm_out<<<dim3(out_size / 4 / 256), 256, 0, stream>>>(out, Lbuf);
}